// Round 2
// baseline (1775.540 us; speedup 1.0000x reference)
//
#include <hip/hip_runtime.h>
#include <hip/hip_bf16.h>
#include <stdint.h>

#define NT 2048      // tokens = B*S
#define DD 1024      // hidden dim
#define FF 4096      // ffn dim
#define NE 8         // experts
#define NSLOT (NT*2) // top-2 slots

typedef float  f32x4  __attribute__((ext_vector_type(4)));
typedef __bf16 bf16x8 __attribute__((ext_vector_type(8)));
typedef __bf16 bf16x4 __attribute__((ext_vector_type(4)));

// async global->LDS, 16B per lane. LDS dest is wave-uniform base + lane*16.
__device__ __forceinline__ void gl16(void* lds, const void* g) {
    __builtin_amdgcn_global_load_lds(
        (const __attribute__((address_space(1))) void*)g,
        (__attribute__((address_space(3))) void*)lds, 16, 0, 0);
}

// ---------------- router: logits, softmax, top-2, renorm; also emits x in bf16 ----------------
__global__ void k_router(const float* __restrict__ x, const float* __restrict__ rw,
                         const float* __restrict__ escale, __bf16* __restrict__ xb,
                         int* __restrict__ counts, int* __restrict__ rank,
                         int* __restrict__ tidx, float* __restrict__ tw) {
    int t = blockIdx.x;
    int lane = threadIdx.x;               // 64 lanes, one wave per token
    const float* xr = x + (size_t)t * DD + lane * 16;
    float4 xv[4];
    #pragma unroll
    for (int c = 0; c < 4; c++) xv[c] = reinterpret_cast<const float4*>(xr)[c];
    // emit bf16 copy of x (one token row per wave)
    #pragma unroll
    for (int c = 0; c < 4; c++) {
        bf16x4 o;
        o[0] = (__bf16)xv[c].x; o[1] = (__bf16)xv[c].y;
        o[2] = (__bf16)xv[c].z; o[3] = (__bf16)xv[c].w;
        *reinterpret_cast<bf16x4*>(xb + (size_t)t * DD + lane * 16 + c * 4) = o;
    }
    float acc[NE];
    #pragma unroll
    for (int e = 0; e < NE; e++) acc[e] = 0.f;
    #pragma unroll
    for (int c = 0; c < 4; c++) {
        #pragma unroll
        for (int e = 0; e < NE; e++) {
            float4 rv = reinterpret_cast<const float4*>(rw + (size_t)e * DD + lane * 16)[c];
            acc[e] += xv[c].x*rv.x + xv[c].y*rv.y + xv[c].z*rv.z + xv[c].w*rv.w;
        }
    }
    #pragma unroll
    for (int e = 0; e < NE; e++) {
        #pragma unroll
        for (int off = 32; off > 0; off >>= 1) acc[e] += __shfl_xor(acc[e], off);
    }
    if (lane == 0) {
        int e0 = 0; float l0 = acc[0];
        #pragma unroll
        for (int e = 1; e < NE; e++) if (acc[e] > l0) { l0 = acc[e]; e0 = e; }
        int e1 = (e0 == 0) ? 1 : 0; float l1 = acc[e1];
        #pragma unroll
        for (int e = 0; e < NE; e++) if (e != e0 && acc[e] > l1) { l1 = acc[e]; e1 = e; }
        float sum = 0.f;
        #pragma unroll
        for (int e = 0; e < NE; e++) sum += __expf(acc[e] - l0);
        float p0 = 1.0f / sum;                 // prob of best
        float p1 = __expf(l1 - l0) / sum;      // prob of 2nd
        // reference renormalizes by softmax over the PROB VALUES
        float z  = __expf(p1 - p0);
        float w0 = 1.0f / (1.0f + z);
        float w1 = 1.0f - w0;
        tidx[t*2+0] = e0; tw[t*2+0] = w0 * escale[e0];
        tidx[t*2+1] = e1; tw[t*2+1] = w1 * escale[e1];
        rank[t*2+0] = atomicAdd(&counts[e0], 1);
        rank[t*2+1] = atomicAdd(&counts[e1], 1);
    }
}

__global__ void k_prefix(const int* __restrict__ counts, int* __restrict__ offsets) {
    if (threadIdx.x == 0) {
        int s = 0;
        for (int e = 0; e < NE; e++) { offsets[e] = s; s += counts[e]; }
        offsets[NE] = s;
    }
}

__global__ void k_scatter(const int* __restrict__ tidx, const float* __restrict__ tw,
                          const int* __restrict__ rank, const int* __restrict__ offsets,
                          int* __restrict__ slot_token, float* __restrict__ slot_w) {
    int t = blockIdx.x * blockDim.x + threadIdx.x;
    if (t >= NT) return;
    #pragma unroll
    for (int k = 0; k < 2; k++) {
        int e = tidx[t*2+k];
        int p = offsets[e] + rank[t*2+k];
        slot_token[p] = t; slot_w[p] = tw[t*2+k];
    }
}

// ---------------- grouped GEMMs (m97 structure: 128x128 tile, BK=32, gload_lds w16) ------------
#define BM 128
#define BN 128
#define BK 32
#define KSPLIT 4

// H[slot, f] = silu( x[token] . w1[e][f][:] );  A bf16 (gathered rows), B fp32 (cvt on LDS read)
__launch_bounds__(256)
__global__ void k_gemm1(const __bf16* __restrict__ xb, const float* __restrict__ w1,
                        const int* __restrict__ offsets, const int* __restrict__ slot_token,
                        __bf16* __restrict__ H) {
    int e = blockIdx.z;
    int base = offsets[e];
    int Me = offsets[e+1] - base;
    int m0 = blockIdx.x * BM;
    if (m0 >= Me) return;
    int n0 = blockIdx.y * BN;   // over FF

    __shared__ __bf16 As[BM*BK];   // 8 KB, linear row-major [128][32]
    __shared__ float  Bs[BN*BK];   // 16 KB, linear row-major [128][32]

    int tid = threadIdx.x, wave = tid >> 6, lane = tid & 63;
    int wm = (wave & 1) * 64, wn = (wave >> 1) * 64;

    // A staging: wave covers chunks c=wave*2+j; chunk = 16 rows; lane -> row c*16+lane/4, col16 lane&3
    const __bf16* aptr[2];
    #pragma unroll
    for (int j = 0; j < 2; j++) {
        int r = (wave*2 + j) * 16 + (lane >> 2);
        int rl = min(m0 + r, Me - 1);
        int tok = slot_token[base + rl];
        aptr[j] = xb + (size_t)tok * DD + (lane & 3) * 8;
    }
    // B staging: wave covers chunks c=wave*4+j; chunk = 8 rows; lane -> row c*8+lane/8, col16 lane&7
    const float* bptr[4];
    #pragma unroll
    for (int j = 0; j < 4; j++) {
        int r = (wave*4 + j) * 8 + (lane >> 3);
        bptr[j] = w1 + ((size_t)e * FF + n0 + r) * DD + (lane & 7) * 4;
    }

    f32x4 acc[4][4];
    #pragma unroll
    for (int m = 0; m < 4; m++)
        #pragma unroll
        for (int n = 0; n < 4; n++) acc[m][n] = (f32x4){0.f,0.f,0.f,0.f};

    for (int k0 = 0; k0 < DD; k0 += BK) {
        #pragma unroll
        for (int j = 0; j < 2; j++) gl16(&As[(wave*2 + j) * 512], aptr[j] + k0);
        #pragma unroll
        for (int j = 0; j < 4; j++) gl16(&Bs[(wave*4 + j) * 256], bptr[j] + k0);
        __syncthreads();
        bf16x8 af[4], bfr[4];
        #pragma unroll
        for (int m = 0; m < 4; m++)
            af[m] = *reinterpret_cast<const bf16x8*>(&As[(wm + m*16 + (lane & 15)) * BK + (lane >> 4) * 8]);
        #pragma unroll
        for (int n = 0; n < 4; n++) {
            const float* p = &Bs[(wn + n*16 + (lane & 15)) * BK + (lane >> 4) * 8];
            float4 x0 = *reinterpret_cast<const float4*>(p);
            float4 x1 = *reinterpret_cast<const float4*>(p + 4);
            bf16x8 t;
            t[0]=(__bf16)x0.x; t[1]=(__bf16)x0.y; t[2]=(__bf16)x0.z; t[3]=(__bf16)x0.w;
            t[4]=(__bf16)x1.x; t[5]=(__bf16)x1.y; t[6]=(__bf16)x1.z; t[7]=(__bf16)x1.w;
            bfr[n] = t;
        }
        #pragma unroll
        for (int m = 0; m < 4; m++)
            #pragma unroll
            for (int n = 0; n < 4; n++)
                acc[m][n] = __builtin_amdgcn_mfma_f32_16x16x32_bf16(af[m], bfr[n], acc[m][n], 0, 0, 0);
        __syncthreads();
    }

    int rbase = wm + (lane >> 4) * 4;
    int cbase = n0 + wn + (lane & 15);
    #pragma unroll
    for (int m = 0; m < 4; m++) {
        #pragma unroll
        for (int j = 0; j < 4; j++) {
            int rl = m0 + rbase + m*16 + j;
            if (rl < Me) {
                #pragma unroll
                for (int n = 0; n < 4; n++) {
                    float v = acc[m][n][j];
                    float s = v / (1.0f + __expf(-v));     // silu
                    H[(size_t)(base + rl) * FF + cbase + n*16] = (__bf16)s;
                }
            }
        }
    }
}

// out[tok,:] += slot_w * ( H[slot] . w2[e][d][:] ), split-K over FF, fp32 atomics
__launch_bounds__(256)
__global__ void k_gemm2(const __bf16* __restrict__ H, const float* __restrict__ w2,
                        const int* __restrict__ offsets,
                        const int* __restrict__ slot_token, const float* __restrict__ slot_w,
                        float* __restrict__ out) {
    int e = blockIdx.z;
    int base = offsets[e];
    int Me = offsets[e+1] - base;
    int mt = blockIdx.x & 15;          // m-tile fastest (B-panel L2 reuse)
    int ch = blockIdx.x >> 4;          // K chunk
    int m0 = mt * BM;
    if (m0 >= Me) return;
    int n0 = blockIdx.y * BN;          // over DD
    const int KCH = FF / KSPLIT;       // 1024
    int kbeg = ch * KCH;

    __shared__ __bf16 As[BM*BK];
    __shared__ float  Bs[BN*BK];

    int tid = threadIdx.x, wave = tid >> 6, lane = tid & 63;
    int wm = (wave & 1) * 64, wn = (wave >> 1) * 64;

    const __bf16* aptr[2];
    #pragma unroll
    for (int j = 0; j < 2; j++) {
        int r = (wave*2 + j) * 16 + (lane >> 2);
        int rl = min(m0 + r, Me - 1);
        aptr[j] = H + (size_t)(base + rl) * FF + kbeg + (lane & 3) * 8;
    }
    const float* bptr[4];
    #pragma unroll
    for (int j = 0; j < 4; j++) {
        int r = (wave*4 + j) * 8 + (lane >> 3);
        bptr[j] = w2 + ((size_t)e * DD + n0 + r) * FF + kbeg + (lane & 7) * 4;
    }

    f32x4 acc[4][4];
    #pragma unroll
    for (int m = 0; m < 4; m++)
        #pragma unroll
        for (int n = 0; n < 4; n++) acc[m][n] = (f32x4){0.f,0.f,0.f,0.f};

    for (int k0 = 0; k0 < KCH; k0 += BK) {
        #pragma unroll
        for (int j = 0; j < 2; j++) gl16(&As[(wave*2 + j) * 512], aptr[j] + k0);
        #pragma unroll
        for (int j = 0; j < 4; j++) gl16(&Bs[(wave*4 + j) * 256], bptr[j] + k0);
        __syncthreads();
        bf16x8 af[4], bfr[4];
        #pragma unroll
        for (int m = 0; m < 4; m++)
            af[m] = *reinterpret_cast<const bf16x8*>(&As[(wm + m*16 + (lane & 15)) * BK + (lane >> 4) * 8]);
        #pragma unroll
        for (int n = 0; n < 4; n++) {
            const float* p = &Bs[(wn + n*16 + (lane & 15)) * BK + (lane >> 4) * 8];
            float4 x0 = *reinterpret_cast<const float4*>(p);
            float4 x1 = *reinterpret_cast<const float4*>(p + 4);
            bf16x8 t;
            t[0]=(__bf16)x0.x; t[1]=(__bf16)x0.y; t[2]=(__bf16)x0.z; t[3]=(__bf16)x0.w;
            t[4]=(__bf16)x1.x; t[5]=(__bf16)x1.y; t[6]=(__bf16)x1.z; t[7]=(__bf16)x1.w;
            bfr[n] = t;
        }
        #pragma unroll
        for (int m = 0; m < 4; m++)
            #pragma unroll
            for (int n = 0; n < 4; n++)
                acc[m][n] = __builtin_amdgcn_mfma_f32_16x16x32_bf16(af[m], bfr[n], acc[m][n], 0, 0, 0);
        __syncthreads();
    }

    int rbase = wm + (lane >> 4) * 4;
    int cb = n0 + wn + (lane & 15);
    #pragma unroll
    for (int m = 0; m < 4; m++) {
        #pragma unroll
        for (int j = 0; j < 4; j++) {
            int rl = m0 + rbase + m*16 + j;
            if (rl < Me) {
                int p = base + rl;
                int tok = slot_token[p];
                float wv = slot_w[p];
                float* yrow = out + (size_t)tok * DD + cb;
                #pragma unroll
                for (int n = 0; n < 4; n++)
                    atomicAdd(&yrow[n*16], acc[m][n][j] * wv);
            }
        }
    }
}

extern "C" void kernel_launch(void* const* d_in, const int* in_sizes, int n_in,
                              void* d_out, int out_size, void* d_ws, size_t ws_size,
                              hipStream_t stream) {
    const float* x  = (const float*)d_in[0];
    const float* rw = (const float*)d_in[1];
    const float* w1 = (const float*)d_in[2];
    const float* w2 = (const float*)d_in[3];
    const float* es = (const float*)d_in[4];
    float* out = (float*)d_out;

    uint8_t* ws = (uint8_t*)d_ws;
    __bf16* xb   = (__bf16*)ws;  ws += (size_t)NT * DD * 2;       // 4 MB
    __bf16* H    = (__bf16*)ws;  ws += (size_t)NSLOT * FF * 2;    // 32 MB
    int*    counts   = (int*)ws; ws += 64;
    int*    offsets  = (int*)ws; ws += 64;
    int*    tidx     = (int*)ws; ws += (size_t)NT * 2 * 4;
    float*  tw       = (float*)ws; ws += (size_t)NT * 2 * 4;
    int*    rank     = (int*)ws; ws += (size_t)NT * 2 * 4;
    int*    slot_token = (int*)ws; ws += (size_t)NSLOT * 4;
    float*  slot_w     = (float*)ws; ws += (size_t)NSLOT * 4;

    hipMemsetAsync(counts, 0, NE * sizeof(int), stream);
    hipMemsetAsync(out, 0, (size_t)NT * DD * sizeof(float), stream);
    k_router<<<NT, 64, 0, stream>>>(x, rw, es, xb, counts, rank, tidx, tw);
    k_prefix<<<1, 1, 0, stream>>>(counts, offsets);
    k_scatter<<<NT / 256, 256, 0, stream>>>(tidx, tw, rank, offsets, slot_token, slot_w);
    dim3 g1(NT / BM, FF / BN, NE);          // m fastest for B-panel L2 reuse
    k_gemm1<<<g1, 256, 0, stream>>>(xb, w1, offsets, slot_token, H);
    dim3 g2((NT / BM) * KSPLIT, DD / BN, NE);
    k_gemm2<<<g2, 256, 0, stream>>>(H, w2, offsets, slot_token, slot_w, out);
}

// Round 4
// 1064.862 us; speedup vs baseline: 1.6674x; 1.6674x over previous
//
#include <hip/hip_runtime.h>
#include <hip/hip_bf16.h>
#include <stdint.h>

#define NT 2048      // tokens = B*S
#define DD 1024      // hidden dim
#define FF 4096      // ffn dim
#define NE 8         // experts
#define NSLOT (NT*2) // top-2 slots

typedef float  f32x4  __attribute__((ext_vector_type(4)));
typedef __bf16 bf16x8 __attribute__((ext_vector_type(8)));
typedef __bf16 bf16x4 __attribute__((ext_vector_type(4)));

// async global->LDS, 16B per lane. LDS dest is wave-uniform base + lane*16 (linear).
__device__ __forceinline__ void gl16(void* lds, const void* g) {
    __builtin_amdgcn_global_load_lds(
        (const __attribute__((address_space(1))) void*)g,
        (__attribute__((address_space(3))) void*)lds, 16, 0, 0);
}

// ---------------- router: logits, softmax, top-2, renorm; also emits x in bf16 ----------------
__global__ void k_router(const float* __restrict__ x, const float* __restrict__ rw,
                         const float* __restrict__ escale, __bf16* __restrict__ xb,
                         int* __restrict__ counts, int* __restrict__ rank,
                         int* __restrict__ tidx, float* __restrict__ tw) {
    int t = blockIdx.x;
    int lane = threadIdx.x;               // 64 lanes, one wave per token
    const float* xr = x + (size_t)t * DD + lane * 16;
    float4 xv[4];
    #pragma unroll
    for (int c = 0; c < 4; c++) xv[c] = reinterpret_cast<const float4*>(xr)[c];
    #pragma unroll
    for (int c = 0; c < 4; c++) {
        bf16x4 o;
        o[0] = (__bf16)xv[c].x; o[1] = (__bf16)xv[c].y;
        o[2] = (__bf16)xv[c].z; o[3] = (__bf16)xv[c].w;
        *reinterpret_cast<bf16x4*>(xb + (size_t)t * DD + lane * 16 + c * 4) = o;
    }
    float acc[NE];
    #pragma unroll
    for (int e = 0; e < NE; e++) acc[e] = 0.f;
    #pragma unroll
    for (int c = 0; c < 4; c++) {
        #pragma unroll
        for (int e = 0; e < NE; e++) {
            float4 rv = reinterpret_cast<const float4*>(rw + (size_t)e * DD + lane * 16)[c];
            acc[e] += xv[c].x*rv.x + xv[c].y*rv.y + xv[c].z*rv.z + xv[c].w*rv.w;
        }
    }
    #pragma unroll
    for (int e = 0; e < NE; e++) {
        #pragma unroll
        for (int off = 32; off > 0; off >>= 1) acc[e] += __shfl_xor(acc[e], off);
    }
    if (lane == 0) {
        int e0 = 0; float l0 = acc[0];
        #pragma unroll
        for (int e = 1; e < NE; e++) if (acc[e] > l0) { l0 = acc[e]; e0 = e; }
        int e1 = (e0 == 0) ? 1 : 0; float l1 = acc[e1];
        #pragma unroll
        for (int e = 0; e < NE; e++) if (e != e0 && acc[e] > l1) { l1 = acc[e]; e1 = e; }
        float sum = 0.f;
        #pragma unroll
        for (int e = 0; e < NE; e++) sum += __expf(acc[e] - l0);
        float p0 = 1.0f / sum;
        float p1 = __expf(l1 - l0) / sum;
        // reference renormalizes by softmax over the PROB VALUES
        float z  = __expf(p1 - p0);
        float w0 = 1.0f / (1.0f + z);
        float w1 = 1.0f - w0;
        tidx[t*2+0] = e0; tw[t*2+0] = w0 * escale[e0];
        tidx[t*2+1] = e1; tw[t*2+1] = w1 * escale[e1];
        rank[t*2+0] = atomicAdd(&counts[e0], 1);
        rank[t*2+1] = atomicAdd(&counts[e1], 1);
    }
}

__global__ void k_prefix(const int* __restrict__ counts, int* __restrict__ offsets) {
    if (threadIdx.x == 0) {
        int s = 0;
        for (int e = 0; e < NE; e++) { offsets[e] = s; s += counts[e]; }
        offsets[NE] = s;
    }
}

__global__ void k_scatter(const int* __restrict__ tidx, const float* __restrict__ tw,
                          const int* __restrict__ rank, const int* __restrict__ offsets,
                          int* __restrict__ slot_token, float* __restrict__ slot_w) {
    int t = blockIdx.x * blockDim.x + threadIdx.x;
    if (t >= NT) return;
    #pragma unroll
    for (int k = 0; k < 2; k++) {
        int e = tidx[t*2+k];
        int p = offsets[e] + rank[t*2+k];
        slot_token[p] = t; slot_w[p] = tw[t*2+k];
    }
}

// ---------------- grouped GEMMs: fragment-major LDS (conflict-free linear ds_read_b128) -------
// A tile (bf16): As[8 subtiles][512] ; elem (ms,q,r,i) = ms*512+q*128+r*8+i holds
//   A[row=ms*16+r][k=q*8+i].  Lane L stages/reads 16B at ms*1024 + L*16 bytes -> linear.
// B tile (fp32): Bs[8 subtiles][512] ; float (ns,h,q,r,i) = ns*512+h*256+q*64+r*4+i holds
//   B[row=ns*16+r][k=q*8+h*4+i]. Lane L reads b128 at ns*2048 + h*1024 + L*16 bytes -> linear.
#define BM 128
#define BN 128
#define BK 32
#define KSPLIT 4

// H[slot, f] = silu( x[token] . w1[e][f][:] )
__launch_bounds__(256)
__global__ void k_gemm1(const __bf16* __restrict__ xb, const float* __restrict__ w1,
                        const int* __restrict__ offsets, const int* __restrict__ slot_token,
                        __bf16* __restrict__ H) {
    int e = blockIdx.z;
    int base = offsets[e];
    int Me = offsets[e+1] - base;
    int m0 = blockIdx.x * BM;
    if (m0 >= Me) return;
    int n0 = blockIdx.y * BN;   // over FF

    __shared__ __bf16 As[8 * 512];   // 8 KB
    __shared__ float  Bs[8 * 512];   // 16 KB

    int tid = threadIdx.x, wave = tid >> 6, lane = tid & 63;
    int q = lane >> 4, r = lane & 15;

    // A staging sources: wave stages subtiles ms = wave*2 + j
    const __bf16* aptr[2];
    #pragma unroll
    for (int j = 0; j < 2; j++) {
        int row = (wave*2 + j) * 16 + r;
        int rl = min(m0 + row, Me - 1);
        int tok = slot_token[base + rl];
        aptr[j] = xb + (size_t)tok * DD + q * 8;
    }
    // B staging sources: wave stages chunks c = wave*4 + j ; ns=c>>1, h=c&1
    const float* bptr[4];
    #pragma unroll
    for (int j = 0; j < 4; j++) {
        int c = wave*4 + j;
        int row = (c >> 1) * 16 + r;
        bptr[j] = w1 + ((size_t)e * FF + n0 + row) * DD + q * 8 + (c & 1) * 4;
    }

    f32x4 acc[4][4];
    #pragma unroll
    for (int m = 0; m < 4; m++)
        #pragma unroll
        for (int n = 0; n < 4; n++) acc[m][n] = (f32x4){0.f,0.f,0.f,0.f};

    for (int k0 = 0; k0 < DD; k0 += BK) {
        #pragma unroll
        for (int j = 0; j < 2; j++) gl16(&As[(wave*2 + j) * 512], aptr[j] + k0);
        #pragma unroll
        for (int j = 0; j < 4; j++) gl16(&Bs[(wave*4 + j) * 256], bptr[j] + k0);
        __syncthreads();
        bf16x8 af[4], bfr[4];
        #pragma unroll
        for (int m = 0; m < 4; m++) {
            int ms = (wave & 1) * 4 + m;
            af[m] = *reinterpret_cast<const bf16x8*>(&As[ms * 512 + lane * 8]);
        }
        #pragma unroll
        for (int n = 0; n < 4; n++) {
            int ns = (wave >> 1) * 4 + n;
            f32x4 x0 = *reinterpret_cast<const f32x4*>(&Bs[ns * 512 + lane * 4]);
            f32x4 x1 = *reinterpret_cast<const f32x4*>(&Bs[ns * 512 + 256 + lane * 4]);
            bf16x8 t;
            t[0]=(__bf16)x0[0]; t[1]=(__bf16)x0[1]; t[2]=(__bf16)x0[2]; t[3]=(__bf16)x0[3];
            t[4]=(__bf16)x1[0]; t[5]=(__bf16)x1[1]; t[6]=(__bf16)x1[2]; t[7]=(__bf16)x1[3];
            bfr[n] = t;
        }
        #pragma unroll
        for (int m = 0; m < 4; m++)
            #pragma unroll
            for (int n = 0; n < 4; n++)
                acc[m][n] = __builtin_amdgcn_mfma_f32_16x16x32_bf16(af[m], bfr[n], acc[m][n], 0, 0, 0);
        __syncthreads();
    }

    int rbase = (wave & 1) * 64 + q * 4;
    int cbase = n0 + (wave >> 1) * 64 + r;
    #pragma unroll
    for (int m = 0; m < 4; m++) {
        #pragma unroll
        for (int j = 0; j < 4; j++) {
            int rl = m0 + rbase + m*16 + j;
            if (rl < Me) {
                #pragma unroll
                for (int n = 0; n < 4; n++) {
                    float v = acc[m][n][j];
                    float s = v / (1.0f + __expf(-v));     // silu
                    H[(size_t)(base + rl) * FF + cbase + n*16] = (__bf16)s;
                }
            }
        }
    }
}

// out[tok,:] += slot_w * ( H[slot] . w2[e][d][:] ), split-K over FF, fp32 atomics
__launch_bounds__(256)
__global__ void k_gemm2(const __bf16* __restrict__ H, const float* __restrict__ w2,
                        const int* __restrict__ offsets,
                        const int* __restrict__ slot_token, const float* __restrict__ slot_w,
                        float* __restrict__ out) {
    int e = blockIdx.z;
    int base = offsets[e];
    int Me = offsets[e+1] - base;
    int mt = blockIdx.x & 15;          // m-tile fastest (B-panel L2 reuse)
    int ch = blockIdx.x >> 4;          // K chunk
    int m0 = mt * BM;
    if (m0 >= Me) return;
    int n0 = blockIdx.y * BN;          // over DD
    const int KCH = FF / KSPLIT;       // 1024
    int kbeg = ch * KCH;

    __shared__ __bf16 As[8 * 512];
    __shared__ float  Bs[8 * 512];

    int tid = threadIdx.x, wave = tid >> 6, lane = tid & 63;
    int q = lane >> 4, r = lane & 15;

    const __bf16* aptr[2];
    #pragma unroll
    for (int j = 0; j < 2; j++) {
        int row = (wave*2 + j) * 16 + r;
        int rl = min(m0 + row, Me - 1);
        aptr[j] = H + (size_t)(base + rl) * FF + kbeg + q * 8;
    }
    const float* bptr[4];
    #pragma unroll
    for (int j = 0; j < 4; j++) {
        int c = wave*4 + j;
        int row = (c >> 1) * 16 + r;
        bptr[j] = w2 + ((size_t)e * DD + n0 + row) * FF + kbeg + q * 8 + (c & 1) * 4;
    }

    f32x4 acc[4][4];
    #pragma unroll
    for (int m = 0; m < 4; m++)
        #pragma unroll
        for (int n = 0; n < 4; n++) acc[m][n] = (f32x4){0.f,0.f,0.f,0.f};

    for (int k0 = 0; k0 < KCH; k0 += BK) {
        #pragma unroll
        for (int j = 0; j < 2; j++) gl16(&As[(wave*2 + j) * 512], aptr[j] + k0);
        #pragma unroll
        for (int j = 0; j < 4; j++) gl16(&Bs[(wave*4 + j) * 256], bptr[j] + k0);
        __syncthreads();
        bf16x8 af[4], bfr[4];
        #pragma unroll
        for (int m = 0; m < 4; m++) {
            int ms = (wave & 1) * 4 + m;
            af[m] = *reinterpret_cast<const bf16x8*>(&As[ms * 512 + lane * 8]);
        }
        #pragma unroll
        for (int n = 0; n < 4; n++) {
            int ns = (wave >> 1) * 4 + n;
            f32x4 x0 = *reinterpret_cast<const f32x4*>(&Bs[ns * 512 + lane * 4]);
            f32x4 x1 = *reinterpret_cast<const f32x4*>(&Bs[ns * 512 + 256 + lane * 4]);
            bf16x8 t;
            t[0]=(__bf16)x0[0]; t[1]=(__bf16)x0[1]; t[2]=(__bf16)x0[2]; t[3]=(__bf16)x0[3];
            t[4]=(__bf16)x1[0]; t[5]=(__bf16)x1[1]; t[6]=(__bf16)x1[2]; t[7]=(__bf16)x1[3];
            bfr[n] = t;
        }
        #pragma unroll
        for (int m = 0; m < 4; m++)
            #pragma unroll
            for (int n = 0; n < 4; n++)
                acc[m][n] = __builtin_amdgcn_mfma_f32_16x16x32_bf16(af[m], bfr[n], acc[m][n], 0, 0, 0);
        __syncthreads();
    }

    int rbase = (wave & 1) * 64 + q * 4;
    int cb = n0 + (wave >> 1) * 64 + r;
    #pragma unroll
    for (int m = 0; m < 4; m++) {
        #pragma unroll
        for (int j = 0; j < 4; j++) {
            int rl = m0 + rbase + m*16 + j;
            if (rl < Me) {
                int p = base + rl;
                int tok = slot_token[p];
                float wv = slot_w[p];
                float* yrow = out + (size_t)tok * DD + cb;
                #pragma unroll
                for (int n = 0; n < 4; n++)
                    atomicAdd(&yrow[n*16], acc[m][n][j] * wv);
            }
        }
    }
}

extern "C" void kernel_launch(void* const* d_in, const int* in_sizes, int n_in,
                              void* d_out, int out_size, void* d_ws, size_t ws_size,
                              hipStream_t stream) {
    const float* x  = (const float*)d_in[0];
    const float* rw = (const float*)d_in[1];
    const float* w1 = (const float*)d_in[2];
    const float* w2 = (const float*)d_in[3];
    const float* es = (const float*)d_in[4];
    float* out = (float*)d_out;

    uint8_t* ws = (uint8_t*)d_ws;
    __bf16* xb   = (__bf16*)ws;  ws += (size_t)NT * DD * 2;       // 4 MB
    __bf16* H    = (__bf16*)ws;  ws += (size_t)NSLOT * FF * 2;    // 32 MB
    int*    counts   = (int*)ws; ws += 64;
    int*    offsets  = (int*)ws; ws += 64;
    int*    tidx     = (int*)ws; ws += (size_t)NT * 2 * 4;
    float*  tw       = (float*)ws; ws += (size_t)NT * 2 * 4;
    int*    rank     = (int*)ws; ws += (size_t)NT * 2 * 4;
    int*    slot_token = (int*)ws; ws += (size_t)NSLOT * 4;
    float*  slot_w     = (float*)ws; ws += (size_t)NSLOT * 4;

    hipMemsetAsync(counts, 0, NE * sizeof(int), stream);
    hipMemsetAsync(out, 0, (size_t)NT * DD * sizeof(float), stream);
    k_router<<<NT, 64, 0, stream>>>(x, rw, es, xb, counts, rank, tidx, tw);
    k_prefix<<<1, 1, 0, stream>>>(counts, offsets);
    k_scatter<<<NT / 256, 256, 0, stream>>>(tidx, tw, rank, offsets, slot_token, slot_w);
    dim3 g1(NT / BM, FF / BN, NE);          // m fastest for B-panel L2 reuse
    k_gemm1<<<g1, 256, 0, stream>>>(xb, w1, offsets, slot_token, H);
    dim3 g2((NT / BM) * KSPLIT, DD / BN, NE);
    k_gemm2<<<g2, 256, 0, stream>>>(H, w2, offsets, slot_token, slot_w, out);
}